// Round 6
// baseline (3323.657 us; speedup 1.0000x reference)
//
#include <hip/hip_runtime.h>
#include <hip/hip_fp16.h>
#include <cstddef>
#include <cstdint>

#define NB 64
#define TT 1024
#define DD 512
#define HH 512
#define SLOTS 4   // batches interleaved per block (latency hiding)

// ---------------------------------------------------------------------------
// packed fp16 dot2: acc += a.lo*b.lo + a.hi*b.hi  (fp32 accumulate)
// ---------------------------------------------------------------------------
typedef _Float16 h2_t __attribute__((ext_vector_type(2)));

__device__ __forceinline__ float dot2f(uint32_t a, uint32_t b, float c) {
#if __has_builtin(__builtin_amdgcn_fdot2)
    return __builtin_amdgcn_fdot2(__builtin_bit_cast(h2_t, a),
                                  __builtin_bit_cast(h2_t, b), c, false);
#else
    __half2 av = __builtin_bit_cast(__half2, a);
    __half2 bv = __builtin_bit_cast(__half2, b);
    float2 af = __half22float2(av), bf = __half22float2(bv);
    return fmaf(af.x, bf.x, fmaf(af.y, bf.y, c));
#endif
}

// fast tanh: |err| ~1e-7, ~6 VALU ops, no branches.
__device__ __forceinline__ float fast_tanh(float z) {
    z = fmaxf(-15.f, fminf(15.f, z));
    float u = __builtin_amdgcn_exp2f(-2.885390082f * z);
    return (1.f - u) * __builtin_amdgcn_rcpf(1.f + u);
}

// ---------------------------------------------------------------------------
// Kernel 1: out[n,t,:] = x[n,t,:] @ Wx + b   (unchanged)
// ---------------------------------------------------------------------------
#define BM 128
#define BN 128
#define BK 8

__global__ __launch_bounds__(256, 2) void gemm_xw(
    const float* __restrict__ A,
    const float* __restrict__ B,
    const float* __restrict__ bias,
    float* __restrict__ C)
{
    __shared__ float As[BK][BM];
    __shared__ float Bs[BK][BN];

    const int tid  = threadIdx.x;
    const int tm   = tid >> 4;
    const int tn   = tid & 15;
    const int row0 = blockIdx.x * BM;
    const int col0 = blockIdx.y * BN;

    const int ar = tid >> 1;
    const int ac = (tid & 1) * 4;
    const int br = tid >> 5;
    const int bc = (tid & 31) * 4;

    float acc[8][8];
#pragma unroll
    for (int i = 0; i < 8; ++i)
#pragma unroll
        for (int j = 0; j < 8; ++j) acc[i][j] = 0.f;

    for (int k0 = 0; k0 < DD; k0 += BK) {
        float4 av = *reinterpret_cast<const float4*>(
            &A[(size_t)(row0 + ar) * DD + k0 + ac]);
        float4 bv = *reinterpret_cast<const float4*>(
            &B[(size_t)(k0 + br) * HH + col0 + bc]);

        As[ac + 0][ar] = av.x;
        As[ac + 1][ar] = av.y;
        As[ac + 2][ar] = av.z;
        As[ac + 3][ar] = av.w;
        *reinterpret_cast<float4*>(&Bs[br][bc]) = bv;
        __syncthreads();

#pragma unroll
        for (int kk = 0; kk < BK; ++kk) {
            float a[8], b[8];
            *reinterpret_cast<float4*>(&a[0]) =
                *reinterpret_cast<const float4*>(&As[kk][tm * 8]);
            *reinterpret_cast<float4*>(&a[4]) =
                *reinterpret_cast<const float4*>(&As[kk][tm * 8 + 4]);
            *reinterpret_cast<float4*>(&b[0]) =
                *reinterpret_cast<const float4*>(&Bs[kk][tn * 8]);
            *reinterpret_cast<float4*>(&b[4]) =
                *reinterpret_cast<const float4*>(&Bs[kk][tn * 8 + 4]);
#pragma unroll
            for (int i = 0; i < 8; ++i)
#pragma unroll
                for (int j = 0; j < 8; ++j)
                    acc[i][j] = fmaf(a[i], b[j], acc[i][j]);
        }
        __syncthreads();
    }

#pragma unroll
    for (int i = 0; i < 8; ++i) {
        const int row = row0 + tm * 8 + i;
#pragma unroll
        for (int j = 0; j < 8; j += 4) {
            const int col = col0 + tn * 8 + j;
            float4 o;
            o.x = acc[i][j + 0] + bias[col + 0];
            o.y = acc[i][j + 1] + bias[col + 1];
            o.z = acc[i][j + 2] + bias[col + 2];
            o.w = acc[i][j + 3] + bias[col + 3];
            *reinterpret_cast<float4*>(&C[(size_t)row * HH + col]) = o;
        }
    }
}

// ---------------------------------------------------------------------------
// Kernel 2: 4-slot interleaved grouped scan.
// 64 blocks x 1024 threads. Block b = (g = b&15, r = b>>4) serves batches
// n = 4g+s (s=0..3), all with role r (columns [r*128, r*128+128)), whose
// packed-fp16 weight slice (32 VGPRs/thread) is SHARED across slots.
// Batch n's 4 roles live on blocks {g, 16+g, 32+g, 48+g} — a closed
// 4-block group, all == g (mod 8) -> same XCD under round-robin (perf only).
//
// Per iteration (all slots at step t):
//   phase A, s=0..3: dot(s) -> partial; B; reduce+tanh+publish(s); B
//   phase B: 1536 remote packets polled by all threads (<=2 each, in
//            publish order); write into hp[s][nxt]; single B.
// Publishing slots ~600cy apart then polling in the same order overlaps
// the ~1500-2600cy L3 round-trip with the other slots' compute.
//
// Exchange protocol IDENTICAL to round 4 (per batch): 8B packet
// {tag=T, fp32 h}, 2-slot parity buffer, single relaxed agent-scope
// atomic store, relaxed agent-scope polling. Replay/poison safety as
// before (stale tags mismatch or carry bit-identical values; 0xAA never
// matches a tag).
//
// Residency: 64 blocks <= #CUs with 16 waves, VGPR<=128, LDS 12.3KB ->
// all co-resident, spin is deadlock-free.
// ---------------------------------------------------------------------------
__global__ __launch_bounds__(1024, 4) void rnn_scan_pkt4(
    const float* __restrict__ Wh,    // (H, H) fp32 row-major
    const float* __restrict__ h0,    // (N, H)
    float* __restrict__ out,         // (N, T, H): in = xw, out = h
    uint64_t* __restrict__ exch)     // [NB][2][HH] tagged packets
{
    __shared__ __align__(16) uint32_t hp[SLOTS][2][HH / 2];  // packed half2 h
    __shared__ float partial[8][128];

    const int b   = blockIdx.x;     // 0..63
    const int g   = b & 15;         // group 0..15
    const int r   = b >> 4;         // role 0..3
    const int jb  = r << 7;         // own column base
    const int tid = threadIdx.x;
    const int col = tid & 127;      // dot: column within slice
    const int sl  = tid >> 7;       // dot: k-slice 0..7 (64 k each)

    // ---- one-time: weight slice -> 32 packed-fp16 regs (shared by slots) --
    uint32_t wreg[32];
    {
        const float* wc = Wh + (size_t)(sl * 64) * HH + jb + col;
#pragma unroll
        for (int p = 0; p < 32; ++p) {
            float e0 = wc[(size_t)(2 * p) * HH];
            float e1 = wc[(size_t)(2 * p + 1) * HH];
            wreg[p] = __builtin_bit_cast(uint32_t, __floats2half2_rn(e0, e1));
        }
    }

    // ---- init h LDS for all 4 slots ----
    for (int q = tid; q < SLOTS * HH; q += 1024) {
        int s = q >> 9, c = q & (HH - 1);
        ((__half*)hp[s][0])[c] =
            __float2half(h0[(size_t)(4 * g + s) * HH + c]);
    }
    __syncthreads();

    // ---- per-slot producer pointers (tid<128 uses them) ----
    float*    outp[SLOTS];
    uint64_t* expub[SLOTS];
#pragma unroll
    for (int s = 0; s < SLOTS; ++s) {
        const int n = 4 * g + s;
        outp[s]  = out + (size_t)n * TT * HH + jb + tid;       // += HH per t
        expub[s] = exch + (size_t)n * 2 * HH + jb + tid;       // + par*HH
    }

    // ---- poll tasks: 1536 = SLOTS*384 remote packets, <=2 per thread ----
    // task ids ordered by slot (publish order). round0: tasks 0..1023 (all
    // threads); round1: tasks 1024..1535 (tid<512).
    int s0 = tid / 384, i0 = tid % 384;
    uint64_t* exr0 = exch + (size_t)(4 * g + s0) * 2 * HH
                   + ((jb + 128 + i0) & (HH - 1));             // + par*HH
    int lds0 = s0 * 1024 + ((jb + 128 + i0) & (HH - 1));       // + nxt*512
    int s1 = 0, i1 = 0, lds1 = 0;
    uint64_t* exr1 = nullptr;
    if (tid < 512) {
        int task = 1024 + tid;
        s1 = task / 384; i1 = task % 384;
        exr1 = exch + (size_t)(4 * g + s1) * 2 * HH
             + ((jb + 128 + i1) & (HH - 1));
        lds1 = s1 * 1024 + ((jb + 128 + i1) & (HH - 1));
    }
    __half* hpflat = (__half*)hp;

    int cur = 0;
    for (int t = 0; t < TT; ++t) {
        const uint32_t T = (uint32_t)(t + 1);
        const int par = (int)(T & 1u);   // exchange parity
        const int nxt = cur ^ 1;         // hp parity for step t's results

        // prefetch all 4 slots' xw (tid<128)
        float xw[SLOTS];
        if (tid < 128) {
#pragma unroll
            for (int s = 0; s < SLOTS; ++s) xw[s] = *outp[s];
        }

        // ---- phase A: dot + publish per slot ----
#pragma unroll
        for (int s = 0; s < SLOTS; ++s) {
            const uint32_t* hpw = &hp[s][cur][sl * 32];
            float a0 = 0.f, a1 = 0.f, a2 = 0.f, a3 = 0.f;
#pragma unroll
            for (int q = 0; q < 8; ++q) {
                uint4 hv = ((const uint4*)hpw)[q];
                a0 = dot2f(hv.x, wreg[4 * q + 0], a0);
                a1 = dot2f(hv.y, wreg[4 * q + 1], a1);
                a2 = dot2f(hv.z, wreg[4 * q + 2], a2);
                a3 = dot2f(hv.w, wreg[4 * q + 3], a3);
            }
            partial[sl][col] = (a0 + a1) + (a2 + a3);
            __syncthreads();

            if (tid < 128) {
                float ssum = 0.f;
#pragma unroll
                for (int k = 0; k < 8; ++k) ssum += partial[k][tid];
                float h = fast_tanh(ssum + xw[s]);
                *outp[s] = h;
                hpflat[s * 1024 + nxt * 512 + jb + tid] = __float2half(h);
                uint64_t pk = ((uint64_t)T << 32) |
                              (uint64_t)__builtin_bit_cast(uint32_t, h);
                __hip_atomic_store(expub[s] + (size_t)par * HH, pk,
                                   __ATOMIC_RELAXED, __HIP_MEMORY_SCOPE_AGENT);
            }
            __syncthreads();
        }

        // ---- phase B: poll remote packets (publish order), fill hp ----
        {
            uint64_t* pa = exr0 + (size_t)par * HH;
            uint64_t v = __hip_atomic_load(pa, __ATOMIC_RELAXED,
                                           __HIP_MEMORY_SCOPE_AGENT);
            while ((uint32_t)(v >> 32) != T) {
                __builtin_amdgcn_s_sleep(1);
                v = __hip_atomic_load(pa, __ATOMIC_RELAXED,
                                      __HIP_MEMORY_SCOPE_AGENT);
            }
            hpflat[lds0 + nxt * 512] =
                __float2half(__builtin_bit_cast(float, (uint32_t)v));
        }
        if (tid < 512) {
            uint64_t* pa = exr1 + (size_t)par * HH;
            uint64_t v = __hip_atomic_load(pa, __ATOMIC_RELAXED,
                                           __HIP_MEMORY_SCOPE_AGENT);
            while ((uint32_t)(v >> 32) != T) {
                __builtin_amdgcn_s_sleep(1);
                v = __hip_atomic_load(pa, __ATOMIC_RELAXED,
                                      __HIP_MEMORY_SCOPE_AGENT);
            }
            hpflat[lds1 + nxt * 512] =
                __float2half(__builtin_bit_cast(float, (uint32_t)v));
        }
        __syncthreads();

#pragma unroll
        for (int s = 0; s < SLOTS; ++s) outp[s] += HH;
        cur ^= 1;
    }
}

// ---------------------------------------------------------------------------
// Fallback scan (no workspace needed)
// ---------------------------------------------------------------------------
__global__ __launch_bounds__(512, 2) void rnn_scan_f32(
    const float* __restrict__ Wh,
    const float* __restrict__ h0,
    float* __restrict__ out)
{
    __shared__ float hbuf[2][HH];
    const int n = blockIdx.x;
    const int j = threadIdx.x;

    hbuf[0][j] = h0[(size_t)n * HH + j];
    __syncthreads();

    float* outn = out + (size_t)n * TT * HH;
    const float* __restrict__ wp = Wh + j;

    int cur = 0;
    for (int t = 0; t < TT; ++t) {
        float acc = outn[(size_t)t * HH + j];
        const float* hc = hbuf[cur];
#pragma unroll 4
        for (int k = 0; k < HH; k += 4) {
            float4 hv = *reinterpret_cast<const float4*>(&hc[k]);
            acc = fmaf(hv.x, wp[(size_t)(k + 0) * HH], acc);
            acc = fmaf(hv.y, wp[(size_t)(k + 1) * HH], acc);
            acc = fmaf(hv.z, wp[(size_t)(k + 2) * HH], acc);
            acc = fmaf(hv.w, wp[(size_t)(k + 3) * HH], acc);
        }
        float hn = tanhf(acc);
        outn[(size_t)t * HH + j] = hn;
        hbuf[cur ^ 1][j] = hn;
        cur ^= 1;
        __syncthreads();
    }
}

// ---------------------------------------------------------------------------
extern "C" void kernel_launch(void* const* d_in, const int* in_sizes, int n_in,
                              void* d_out, int out_size, void* d_ws, size_t ws_size,
                              hipStream_t stream) {
    const float* x  = (const float*)d_in[0];   // (N, T, D)
    const float* h0 = (const float*)d_in[1];   // (N, H)
    const float* Wx = (const float*)d_in[2];   // (D, H)
    const float* Wh = (const float*)d_in[3];   // (H, H)
    const float* b  = (const float*)d_in[4];   // (H)
    float* out = (float*)d_out;                // (N, T, H)

    dim3 g1((NB * TT) / BM, HH / BN);
    gemm_xw<<<g1, 256, 0, stream>>>(x, Wx, b, out);

    const size_t need = (size_t)NB * 2 * HH * sizeof(uint64_t);  // 512 KB
    if (ws_size >= need) {
        rnn_scan_pkt4<<<64, 1024, 0, stream>>>(Wh, h0, out, (uint64_t*)d_ws);
    } else {
        rnn_scan_f32<<<NB, 512, 0, stream>>>(Wh, h0, out);
    }
}

// Round 7
// 2771.217 us; speedup vs baseline: 1.1993x; 1.1993x over previous
//
#include <hip/hip_runtime.h>
#include <hip/hip_fp16.h>
#include <cstddef>
#include <cstdint>

#define NB 64
#define TT 1024
#define DD 512
#define HH 512

// ---------------------------------------------------------------------------
// packed fp16 dot2: acc += a.lo*b.lo + a.hi*b.hi  (fp32 accumulate)
// ---------------------------------------------------------------------------
typedef _Float16 h2_t __attribute__((ext_vector_type(2)));

__device__ __forceinline__ float dot2f(uint32_t a, uint32_t b, float c) {
#if __has_builtin(__builtin_amdgcn_fdot2)
    return __builtin_amdgcn_fdot2(__builtin_bit_cast(h2_t, a),
                                  __builtin_bit_cast(h2_t, b), c, false);
#else
    __half2 av = __builtin_bit_cast(__half2, a);
    __half2 bv = __builtin_bit_cast(__half2, b);
    float2 af = __half22float2(av), bf = __half22float2(bv);
    return fmaf(af.x, bf.x, fmaf(af.y, bf.y, c));
#endif
}

// fast tanh: |err| ~1e-7, ~6 VALU ops (validated round 5: absmax unchanged)
__device__ __forceinline__ float fast_tanh(float z) {
    z = fmaxf(-15.f, fminf(15.f, z));
    float u = __builtin_amdgcn_exp2f(-2.885390082f * z);
    return (1.f - u) * __builtin_amdgcn_rcpf(1.f + u);
}

// ---------------------------------------------------------------------------
// Kernel 1: out[n,t,:] = x[n,t,:] @ Wx + b   (unchanged)
// ---------------------------------------------------------------------------
#define BM 128
#define BN 128
#define BK 8

__global__ __launch_bounds__(256, 2) void gemm_xw(
    const float* __restrict__ A,
    const float* __restrict__ B,
    const float* __restrict__ bias,
    float* __restrict__ C)
{
    __shared__ float As[BK][BM];
    __shared__ float Bs[BK][BN];

    const int tid  = threadIdx.x;
    const int tm   = tid >> 4;
    const int tn   = tid & 15;
    const int row0 = blockIdx.x * BM;
    const int col0 = blockIdx.y * BN;

    const int ar = tid >> 1;
    const int ac = (tid & 1) * 4;
    const int br = tid >> 5;
    const int bc = (tid & 31) * 4;

    float acc[8][8];
#pragma unroll
    for (int i = 0; i < 8; ++i)
#pragma unroll
        for (int j = 0; j < 8; ++j) acc[i][j] = 0.f;

    for (int k0 = 0; k0 < DD; k0 += BK) {
        float4 av = *reinterpret_cast<const float4*>(
            &A[(size_t)(row0 + ar) * DD + k0 + ac]);
        float4 bv = *reinterpret_cast<const float4*>(
            &B[(size_t)(k0 + br) * HH + col0 + bc]);

        As[ac + 0][ar] = av.x;
        As[ac + 1][ar] = av.y;
        As[ac + 2][ar] = av.z;
        As[ac + 3][ar] = av.w;
        *reinterpret_cast<float4*>(&Bs[br][bc]) = bv;
        __syncthreads();

#pragma unroll
        for (int kk = 0; kk < BK; ++kk) {
            float a[8], b[8];
            *reinterpret_cast<float4*>(&a[0]) =
                *reinterpret_cast<const float4*>(&As[kk][tm * 8]);
            *reinterpret_cast<float4*>(&a[4]) =
                *reinterpret_cast<const float4*>(&As[kk][tm * 8 + 4]);
            *reinterpret_cast<float4*>(&b[0]) =
                *reinterpret_cast<const float4*>(&Bs[kk][tn * 8]);
            *reinterpret_cast<float4*>(&b[4]) =
                *reinterpret_cast<const float4*>(&Bs[kk][tn * 8 + 4]);
#pragma unroll
            for (int i = 0; i < 8; ++i)
#pragma unroll
                for (int j = 0; j < 8; ++j)
                    acc[i][j] = fmaf(a[i], b[j], acc[i][j]);
        }
        __syncthreads();
    }

#pragma unroll
    for (int i = 0; i < 8; ++i) {
        const int row = row0 + tm * 8 + i;
#pragma unroll
        for (int j = 0; j < 8; j += 4) {
            const int col = col0 + tn * 8 + j;
            float4 o;
            o.x = acc[i][j + 0] + bias[col + 0];
            o.y = acc[i][j + 1] + bias[col + 1];
            o.z = acc[i][j + 2] + bias[col + 2];
            o.w = acc[i][j + 3] + bias[col + 3];
            *reinterpret_cast<float4*>(&C[(size_t)row * HH + col]) = o;
        }
    }
}

// ---------------------------------------------------------------------------
// Kernel 2: grouped scan = EXACT round-4 structure (proven 1.42 us/step)
// + dual-region exchange:
//   truth  [NB][2][HH]: relaxed agent-scope (sc1) packets  — always correct
//   mirror [NB][2][HH]: plain stores -> producer XCD's L2  — fast path when
//                       the 4 group blocks share an XCD (blk == n mod 8
//                       under round-robin dispatch)
// Consumers spin sc0 (L1-bypass) on the mirror; every 8th failed spin
// checks the truth copy (so wrong placement degrades to round-4 speed,
// never deadlocks). SEPARATE addresses -> the sc1 write-through cannot
// invalidate the mirror line (round-5 failure mode eliminated).
// Packet/tag/parity/replay safety unchanged from round 4 (holds per copy).
//
// Residency: 16 waves, VGPR<=128 (launch_bounds(1024,4)), LDS 10 KB,
// grid=256=#CUs -> all blocks co-resident, spin is deadlock-free.
// ---------------------------------------------------------------------------
__global__ __launch_bounds__(1024, 4) void rnn_scan_pkt(
    const float* __restrict__ Wh,     // (H, H) fp32 row-major
    const float* __restrict__ h0,     // (N, H)
    float* __restrict__ out,          // (N, T, H): in = xw, out = h
    uint64_t* __restrict__ truth,     // [NB][2][HH] sc1 packets
    uint64_t* __restrict__ mirror)    // [NB][2][HH] L2-resident packets
{
    __shared__ __align__(16) uint32_t hp[2][HH / 2];  // packed half2 h
    __shared__ float partial[16][128];

    const int blk = blockIdx.x;
    const int x = blk & 7;
    const int i = blk >> 3;
    const int n = x + ((i & 7) << 3);  // batch 0..63  (n == blk mod 8 -> XCD)
    const int r = i >> 3;              // role 0..3
    const int jb = r << 7;             // column base r*128

    const int tid = threadIdx.x;
    const int w = tid >> 6;            // wave 0..15 -> k slice [w*32, w*32+32)
    const int l = tid & 63;            // lane -> columns jb+l, jb+64+l

    // ---- one-time: weight slice -> registers as packed fp16 ----
    uint32_t w0[16], w1[16];
    {
        const float* wc = Wh + (size_t)(w * 32) * HH + jb + l;
#pragma unroll
        for (int p = 0; p < 16; ++p) {
            float e0 = wc[(size_t)(2 * p) * HH];
            float e1 = wc[(size_t)(2 * p + 1) * HH];
            w0[p] = __builtin_bit_cast(uint32_t, __floats2half2_rn(e0, e1));
            float f0 = wc[(size_t)(2 * p) * HH + 64];
            float f1 = wc[(size_t)(2 * p + 1) * HH + 64];
            w1[p] = __builtin_bit_cast(uint32_t, __floats2half2_rn(f0, f1));
        }
    }

    if (tid < HH)
        ((__half*)hp[0])[tid] = __float2half(h0[(size_t)n * HH + tid]);
    __syncthreads();

    float* outn = out + (size_t)n * TT * HH;
    uint64_t* tru = truth  + (size_t)n * 2 * HH;
    uint64_t* mir = mirror + (size_t)n * 2 * HH;

    // remote column for poller threads (tid 128..511)
    const int rcol = (jb + 128 + (tid - 128)) & (HH - 1);

    int cur = 0;
    for (int t = 0; t < TT; ++t) {
        const uint32_t T = (uint32_t)(t + 1);
        const int slot = (int)(T & 1u);

        // prefetch this step's xw for own columns (consumed after B1)
        float xw_r = 0.f;
        if (tid < 128) xw_r = outn[(size_t)t * HH + jb + tid];

        // partial dot over k slice [w*32, w*32+32) for cols jb+l, jb+64+l
        const uint32_t* hpw = &hp[cur][w * 16];
        float a0 = 0.f, a1 = 0.f, b0 = 0.f, b1 = 0.f;
#pragma unroll
        for (int q = 0; q < 4; ++q) {
            uint4 hv = ((const uint4*)hpw)[q];
            a0 = dot2f(hv.x, w0[4 * q + 0], a0);
            b0 = dot2f(hv.x, w1[4 * q + 0], b0);
            a1 = dot2f(hv.y, w0[4 * q + 1], a1);
            b1 = dot2f(hv.y, w1[4 * q + 1], b1);
            a0 = dot2f(hv.z, w0[4 * q + 2], a0);
            b0 = dot2f(hv.z, w1[4 * q + 2], b0);
            a1 = dot2f(hv.w, w0[4 * q + 3], a1);
            b1 = dot2f(hv.w, w1[4 * q + 3], b1);
        }
        partial[w][l] = a0 + a1;
        partial[w][64 + l] = b0 + b1;
        __syncthreads();                                      // B1

        __half* hpn = (__half*)hp[cur ^ 1];
        if (tid < 128) {
            // waves 0-1: reduce + tanh + write out + publish mirror then truth
            float s = 0.f;
#pragma unroll
            for (int ww = 0; ww < 16; ++ww) s += partial[ww][tid];
            float h = fast_tanh(s + xw_r);
            outn[(size_t)t * HH + jb + tid] = h;
            hpn[jb + tid] = __float2half(h);
            uint64_t pk = ((uint64_t)T << 32) |
                          (uint64_t)__builtin_bit_cast(uint32_t, h);
            const int off = slot * HH + jb + tid;
            // (1) plain store -> this XCD's L2 (separate address!)
            asm volatile("global_store_dwordx2 %0, %1, off"
                         :: "v"((uint64_t)&mir[off]), "v"(pk) : "memory");
            // (2) agent-scope store -> truth copy (correct any placement)
            __hip_atomic_store(&tru[off], pk, __ATOMIC_RELAXED,
                               __HIP_MEMORY_SCOPE_AGENT);
        } else if (tid < 512) {
            // waves 2-7: poll one remote packet; mirror (sc0) fast path,
            // truth (agent) fallback every 8th spin.
            const int off = slot * HH + rcol;
            uint64_t maddr = (uint64_t)&mir[off];
            uint64_t v;
            int spins = 0;
            while (true) {
                asm volatile("global_load_dwordx2 %0, %1, off sc0\n\t"
                             "s_waitcnt vmcnt(0)"
                             : "=v"(v) : "v"(maddr));
                if ((uint32_t)(v >> 32) == T) break;
                if ((++spins & 7) == 0) {
                    v = __hip_atomic_load(&tru[off], __ATOMIC_RELAXED,
                                          __HIP_MEMORY_SCOPE_AGENT);
                    if ((uint32_t)(v >> 32) == T) break;
                    __builtin_amdgcn_s_sleep(1);
                }
            }
            hpn[rcol] = __float2half(__builtin_bit_cast(float, (uint32_t)v));
        }
        __syncthreads();                                      // B2
        cur ^= 1;
    }
}

// ---------------------------------------------------------------------------
// Fallback scan (no workspace needed)
// ---------------------------------------------------------------------------
__global__ __launch_bounds__(512, 2) void rnn_scan_f32(
    const float* __restrict__ Wh,
    const float* __restrict__ h0,
    float* __restrict__ out)
{
    __shared__ float hbuf[2][HH];
    const int n = blockIdx.x;
    const int j = threadIdx.x;

    hbuf[0][j] = h0[(size_t)n * HH + j];
    __syncthreads();

    float* outn = out + (size_t)n * TT * HH;
    const float* __restrict__ wp = Wh + j;

    int cur = 0;
    for (int t = 0; t < TT; ++t) {
        float acc = outn[(size_t)t * HH + j];
        const float* hc = hbuf[cur];
#pragma unroll 4
        for (int k = 0; k < HH; k += 4) {
            float4 hv = *reinterpret_cast<const float4*>(&hc[k]);
            acc = fmaf(hv.x, wp[(size_t)(k + 0) * HH], acc);
            acc = fmaf(hv.y, wp[(size_t)(k + 1) * HH], acc);
            acc = fmaf(hv.z, wp[(size_t)(k + 2) * HH], acc);
            acc = fmaf(hv.w, wp[(size_t)(k + 3) * HH], acc);
        }
        float hn = tanhf(acc);
        outn[(size_t)t * HH + j] = hn;
        hbuf[cur ^ 1][j] = hn;
        cur ^= 1;
        __syncthreads();
    }
}

// ---------------------------------------------------------------------------
extern "C" void kernel_launch(void* const* d_in, const int* in_sizes, int n_in,
                              void* d_out, int out_size, void* d_ws, size_t ws_size,
                              hipStream_t stream) {
    const float* x  = (const float*)d_in[0];   // (N, T, D)
    const float* h0 = (const float*)d_in[1];   // (N, H)
    const float* Wx = (const float*)d_in[2];   // (D, H)
    const float* Wh = (const float*)d_in[3];   // (H, H)
    const float* b  = (const float*)d_in[4];   // (H)
    float* out = (float*)d_out;                // (N, T, H)

    dim3 g1((NB * TT) / BM, HH / BN);
    gemm_xw<<<g1, 256, 0, stream>>>(x, Wx, b, out);

    const size_t region = (size_t)NB * 2 * HH * sizeof(uint64_t);  // 512 KB
    if (ws_size >= 2 * region) {
        uint64_t* truth  = (uint64_t*)d_ws;
        uint64_t* mirror = (uint64_t*)((char*)d_ws + region);
        rnn_scan_pkt<<<256, 1024, 0, stream>>>(Wh, h0, out, truth, mirror);
    } else {
        rnn_scan_f32<<<NB, 512, 0, stream>>>(Wh, h0, out);
    }
}

// Round 8
// 1470.884 us; speedup vs baseline: 2.2596x; 1.8840x over previous
//
#include <hip/hip_runtime.h>
#include <hip/hip_fp16.h>
#include <cstddef>
#include <cstdint>

#define NB 64
#define TT 1024
#define DD 512
#define HH 512

typedef _Float16 h2_t __attribute__((ext_vector_type(2)));
typedef __attribute__((ext_vector_type(8))) short bf16x8;
typedef __attribute__((ext_vector_type(4))) float f32x4;
typedef __attribute__((ext_vector_type(8))) unsigned short ushort8;

__device__ __forceinline__ float dot2f(uint32_t a, uint32_t b, float c) {
#if __has_builtin(__builtin_amdgcn_fdot2)
    return __builtin_amdgcn_fdot2(__builtin_bit_cast(h2_t, a),
                                  __builtin_bit_cast(h2_t, b), c, false);
#else
    __half2 av = __builtin_bit_cast(__half2, a);
    __half2 bv = __builtin_bit_cast(__half2, b);
    float2 af = __half22float2(av), bf = __half22float2(bv);
    return fmaf(af.x, bf.x, fmaf(af.y, bf.y, c));
#endif
}

// fast tanh: |err| ~1e-7 (validated r5: absmax unchanged)
__device__ __forceinline__ float fast_tanh(float z) {
    z = fmaxf(-15.f, fminf(15.f, z));
    float u = __builtin_amdgcn_exp2f(-2.885390082f * z);
    return (1.f - u) * __builtin_amdgcn_rcpf(1.f + u);
}

// fp32 -> bf16 bits, round-to-nearest-even
__device__ __forceinline__ unsigned short f2bf(float f) {
    uint32_t u = __builtin_bit_cast(uint32_t, f);
    u += 0x7FFFu + ((u >> 16) & 1u);
    return (unsigned short)(u >> 16);
}

// ---------------------------------------------------------------------------
// Prep A: x (fp32) -> xb (bf16), 33.55M elems, grid-stride, 8 elems/thread
// ---------------------------------------------------------------------------
__global__ void conv_x(const float* __restrict__ x,
                       unsigned short* __restrict__ xb, long total) {
    long i0 = (long)(blockIdx.x * blockDim.x + threadIdx.x) * 8;
    long stride = (long)gridDim.x * blockDim.x * 8;
    for (long i = i0; i < total; i += stride) {
        float4 a = *reinterpret_cast<const float4*>(&x[i]);
        float4 b = *reinterpret_cast<const float4*>(&x[i + 4]);
        ushort8 o;
        o[0] = f2bf(a.x); o[1] = f2bf(a.y); o[2] = f2bf(a.z); o[3] = f2bf(a.w);
        o[4] = f2bf(b.x); o[5] = f2bf(b.y); o[6] = f2bf(b.z); o[7] = f2bf(b.w);
        *reinterpret_cast<ushort8*>(&xb[i]) = o;
    }
}

// ---------------------------------------------------------------------------
// Prep B: Wt[n][k] = bf16(Wx[k][n])  (512x512 transpose+convert, tiny)
// grid 512 blocks x 64 threads; thread: n=blockIdx, k-chunk of 8
// ---------------------------------------------------------------------------
__global__ void conv_wt(const float* __restrict__ W,
                        unsigned short* __restrict__ Wt) {
    int n = blockIdx.x;
    int kc = threadIdx.x;   // 0..63
    ushort8 o;
#pragma unroll
    for (int i = 0; i < 8; ++i)
        o[i] = f2bf(W[(size_t)(kc * 8 + i) * HH + n]);
    *reinterpret_cast<ushort8*>(&Wt[(size_t)n * DD + kc * 8]) = o;
}

// ---------------------------------------------------------------------------
// Kernel 1 (fast): C[m][n] = xb[m][:] @ Wt[n][:]^T + bias   via MFMA bf16
// 128x128 tile, BK=64, 256 threads (4 waves as 2x2), 16x16x32 MFMA.
// LDS rows padded +8 halfs (stride 72) -> 128B-stride bank conflict killed.
// Frag maps (16x16x32): A/B lane l, reg r -> elem [l&15][(l>>4)*8 + r];
// C lane l, reg r -> row (l>>4)*4+r, col l&15 (m89/m101-verified family).
// ---------------------------------------------------------------------------
#define GBM 128
#define GBN 128
#define GBK 64
#define LDSW 72   // padded row stride in halfs

__global__ __launch_bounds__(256, 4) void gemm_bf16(
    const unsigned short* __restrict__ A,   // (M, K) bf16 row-major
    const unsigned short* __restrict__ Bt,  // (N, K) bf16 row-major (= Wx^T)
    const float* __restrict__ bias,         // (H)
    float* __restrict__ C)                  // (M, H) fp32
{
    __shared__ unsigned short As[GBM * LDSW];
    __shared__ unsigned short Bs[GBN * LDSW];

    const int tid  = threadIdx.x;
    const int m0   = blockIdx.x * GBM;
    const int n0   = blockIdx.y * GBN;
    const int lane = tid & 63;
    const int wave = tid >> 6;
    const int wm   = wave >> 1;          // 0..1
    const int wn   = wave & 1;           // 0..1

    // staging map: 32 rows/pass x 8 chunks of 8 halfs (16B), 4 passes
    const int srow = tid >> 3;           // 0..31
    const int sch  = tid & 7;            // 0..7

    f32x4 acc[4][4] = {};

    const int arow = wm * 64 + (lane & 15);
    const int brow = wn * 64 + (lane & 15);
    const int koff = (lane >> 4) * 8;

    for (int kt = 0; kt < DD / GBK; ++kt) {
        const int k0 = kt * GBK;
#pragma unroll
        for (int p = 0; p < 4; ++p) {
            const int row = srow + p * 32;
            *reinterpret_cast<ushort8*>(&As[row * LDSW + sch * 8]) =
                *reinterpret_cast<const ushort8*>(
                    &A[(size_t)(m0 + row) * DD + k0 + sch * 8]);
            *reinterpret_cast<ushort8*>(&Bs[row * LDSW + sch * 8]) =
                *reinterpret_cast<const ushort8*>(
                    &Bt[(size_t)(n0 + row) * DD + k0 + sch * 8]);
        }
        __syncthreads();

#pragma unroll
        for (int kk = 0; kk < GBK; kk += 32) {
            bf16x8 af[4], bf[4];
#pragma unroll
            for (int mt = 0; mt < 4; ++mt)
                af[mt] = *reinterpret_cast<const bf16x8*>(
                    &As[(arow + mt * 16) * LDSW + kk + koff]);
#pragma unroll
            for (int nt = 0; nt < 4; ++nt)
                bf[nt] = *reinterpret_cast<const bf16x8*>(
                    &Bs[(brow + nt * 16) * LDSW + kk + koff]);
#pragma unroll
            for (int mt = 0; mt < 4; ++mt)
#pragma unroll
                for (int nt = 0; nt < 4; ++nt)
                    acc[mt][nt] = __builtin_amdgcn_mfma_f32_16x16x32_bf16(
                        af[mt], bf[nt], acc[mt][nt], 0, 0, 0);
        }
        __syncthreads();
    }

    // epilogue: C row = m0+wm*64+mt*16+(lane>>4)*4+r, col = n0+wn*64+nt*16+(lane&15)
#pragma unroll
    for (int nt = 0; nt < 4; ++nt) {
        const int col = n0 + wn * 64 + nt * 16 + (lane & 15);
        const float bv = bias[col];
#pragma unroll
        for (int mt = 0; mt < 4; ++mt) {
            const int rbase = m0 + wm * 64 + mt * 16 + (lane >> 4) * 4;
#pragma unroll
            for (int r = 0; r < 4; ++r)
                C[(size_t)(rbase + r) * HH + col] = acc[mt][nt][r] + bv;
        }
    }
}

// ---------------------------------------------------------------------------
// Kernel 1 (fallback): fp32 VALU GEMM (round-1 proven)
// ---------------------------------------------------------------------------
#define BM 128
#define BN 128
#define BK 8

__global__ __launch_bounds__(256, 2) void gemm_xw(
    const float* __restrict__ A,
    const float* __restrict__ B,
    const float* __restrict__ bias,
    float* __restrict__ C)
{
    __shared__ float As[BK][BM];
    __shared__ float Bs[BK][BN];

    const int tid  = threadIdx.x;
    const int tm   = tid >> 4;
    const int tn   = tid & 15;
    const int row0 = blockIdx.x * BM;
    const int col0 = blockIdx.y * BN;

    const int ar = tid >> 1;
    const int ac = (tid & 1) * 4;
    const int br = tid >> 5;
    const int bc = (tid & 31) * 4;

    float acc[8][8];
#pragma unroll
    for (int i = 0; i < 8; ++i)
#pragma unroll
        for (int j = 0; j < 8; ++j) acc[i][j] = 0.f;

    for (int k0 = 0; k0 < DD; k0 += BK) {
        float4 av = *reinterpret_cast<const float4*>(
            &A[(size_t)(row0 + ar) * DD + k0 + ac]);
        float4 bv = *reinterpret_cast<const float4*>(
            &B[(size_t)(k0 + br) * HH + col0 + bc]);

        As[ac + 0][ar] = av.x;
        As[ac + 1][ar] = av.y;
        As[ac + 2][ar] = av.z;
        As[ac + 3][ar] = av.w;
        *reinterpret_cast<float4*>(&Bs[br][bc]) = bv;
        __syncthreads();

#pragma unroll
        for (int kk = 0; kk < BK; ++kk) {
            float a[8], b[8];
            *reinterpret_cast<float4*>(&a[0]) =
                *reinterpret_cast<const float4*>(&As[kk][tm * 8]);
            *reinterpret_cast<float4*>(&a[4]) =
                *reinterpret_cast<const float4*>(&As[kk][tm * 8 + 4]);
            *reinterpret_cast<float4*>(&b[0]) =
                *reinterpret_cast<const float4*>(&Bs[kk][tn * 8]);
            *reinterpret_cast<float4*>(&b[4]) =
                *reinterpret_cast<const float4*>(&Bs[kk][tn * 8 + 4]);
#pragma unroll
            for (int i = 0; i < 8; ++i)
#pragma unroll
                for (int j = 0; j < 8; ++j)
                    acc[i][j] = fmaf(a[i], b[j], acc[i][j]);
        }
        __syncthreads();
    }

#pragma unroll
    for (int i = 0; i < 8; ++i) {
        const int row = row0 + tm * 8 + i;
#pragma unroll
        for (int j = 0; j < 8; j += 4) {
            const int col = col0 + tn * 8 + j;
            float4 o;
            o.x = acc[i][j + 0] + bias[col + 0];
            o.y = acc[i][j + 1] + bias[col + 1];
            o.z = acc[i][j + 2] + bias[col + 2];
            o.w = acc[i][j + 3] + bias[col + 3];
            *reinterpret_cast<float4*>(&C[(size_t)row * HH + col]) = o;
        }
    }
}

// ---------------------------------------------------------------------------
// Kernel 2: grouped scan — EXACT round-4 structure (best measured:
// 1.42 us/step). 256 blocks x 1024 threads; 4 blocks/batch; weight slice
// register-resident packed fp16; tagged 8B packets, 2-slot parity, single
// relaxed agent-scope store, relaxed agent-scope poll. Replay-safe (stale
// tags mismatch or carry bit-identical deterministic values; 0xAA poison
// never matches a tag).
// ---------------------------------------------------------------------------
__global__ __launch_bounds__(1024, 4) void rnn_scan_pkt(
    const float* __restrict__ Wh,    // (H, H) fp32 row-major
    const float* __restrict__ h0,    // (N, H)
    float* __restrict__ out,         // (N, T, H): in = xw, out = h
    uint64_t* __restrict__ exch)     // [NB][2][HH] tagged packets
{
    __shared__ __align__(16) uint32_t hp[2][HH / 2];  // packed half2 h
    __shared__ float partial[16][128];

    const int blk = blockIdx.x;
    const int x = blk & 7;
    const int i = blk >> 3;
    const int n = x + ((i & 7) << 3);  // batch 0..63
    const int r = i >> 3;              // role 0..3
    const int jb = r << 7;             // column base r*128

    const int tid = threadIdx.x;
    const int w = tid >> 6;            // wave 0..15 -> k slice [w*32, w*32+32)
    const int l = tid & 63;            // lane -> columns jb+l, jb+64+l

    uint32_t w0[16], w1[16];
    {
        const float* wc = Wh + (size_t)(w * 32) * HH + jb + l;
#pragma unroll
        for (int p = 0; p < 16; ++p) {
            float e0 = wc[(size_t)(2 * p) * HH];
            float e1 = wc[(size_t)(2 * p + 1) * HH];
            w0[p] = __builtin_bit_cast(uint32_t, __floats2half2_rn(e0, e1));
            float f0 = wc[(size_t)(2 * p) * HH + 64];
            float f1 = wc[(size_t)(2 * p + 1) * HH + 64];
            w1[p] = __builtin_bit_cast(uint32_t, __floats2half2_rn(f0, f1));
        }
    }

    if (tid < HH)
        ((__half*)hp[0])[tid] = __float2half(h0[(size_t)n * HH + tid]);
    __syncthreads();

    float* outn = out + (size_t)n * TT * HH;
    uint64_t* ex = exch + (size_t)n * 2 * HH;

    const int rcol = (jb + 128 + (tid - 128)) & (HH - 1);

    int cur = 0;
    for (int t = 0; t < TT; ++t) {
        const uint32_t T = (uint32_t)(t + 1);
        const int slot = (int)(T & 1u);

        float xw_r = 0.f;
        if (tid < 128) xw_r = outn[(size_t)t * HH + jb + tid];

        const uint32_t* hpw = &hp[cur][w * 16];
        float a0 = 0.f, a1 = 0.f, b0 = 0.f, b1 = 0.f;
#pragma unroll
        for (int q = 0; q < 4; ++q) {
            uint4 hv = ((const uint4*)hpw)[q];
            a0 = dot2f(hv.x, w0[4 * q + 0], a0);
            b0 = dot2f(hv.x, w1[4 * q + 0], b0);
            a1 = dot2f(hv.y, w0[4 * q + 1], a1);
            b1 = dot2f(hv.y, w1[4 * q + 1], b1);
            a0 = dot2f(hv.z, w0[4 * q + 2], a0);
            b0 = dot2f(hv.z, w1[4 * q + 2], b0);
            a1 = dot2f(hv.w, w0[4 * q + 3], a1);
            b1 = dot2f(hv.w, w1[4 * q + 3], b1);
        }
        partial[w][l] = a0 + a1;
        partial[w][64 + l] = b0 + b1;
        __syncthreads();                                      // B1

        __half* hpn = (__half*)hp[cur ^ 1];
        if (tid < 128) {
            float s = 0.f;
#pragma unroll
            for (int ww = 0; ww < 16; ++ww) s += partial[ww][tid];
            float h = fast_tanh(s + xw_r);
            outn[(size_t)t * HH + jb + tid] = h;
            hpn[jb + tid] = __float2half(h);
            uint64_t pk = ((uint64_t)T << 32) |
                          (uint64_t)__builtin_bit_cast(uint32_t, h);
            __hip_atomic_store(&ex[slot * HH + jb + tid], pk,
                               __ATOMIC_RELAXED, __HIP_MEMORY_SCOPE_AGENT);
        } else if (tid < 512) {
            uint64_t pk = __hip_atomic_load(&ex[slot * HH + rcol],
                                            __ATOMIC_RELAXED,
                                            __HIP_MEMORY_SCOPE_AGENT);
            while ((uint32_t)(pk >> 32) != T) {
                __builtin_amdgcn_s_sleep(1);
                pk = __hip_atomic_load(&ex[slot * HH + rcol],
                                       __ATOMIC_RELAXED,
                                       __HIP_MEMORY_SCOPE_AGENT);
            }
            hpn[rcol] = __float2half(__builtin_bit_cast(float, (uint32_t)pk));
        }
        __syncthreads();                                      // B2
        cur ^= 1;
    }
}

// ---------------------------------------------------------------------------
// Fallback scan (no workspace needed)
// ---------------------------------------------------------------------------
__global__ __launch_bounds__(512, 2) void rnn_scan_f32(
    const float* __restrict__ Wh,
    const float* __restrict__ h0,
    float* __restrict__ out)
{
    __shared__ float hbuf[2][HH];
    const int n = blockIdx.x;
    const int j = threadIdx.x;

    hbuf[0][j] = h0[(size_t)n * HH + j];
    __syncthreads();

    float* outn = out + (size_t)n * TT * HH;
    const float* __restrict__ wp = Wh + j;

    int cur = 0;
    for (int t = 0; t < TT; ++t) {
        float acc = outn[(size_t)t * HH + j];
        const float* hc = hbuf[cur];
#pragma unroll 4
        for (int k = 0; k < HH; k += 4) {
            float4 hv = *reinterpret_cast<const float4*>(&hc[k]);
            acc = fmaf(hv.x, wp[(size_t)(k + 0) * HH], acc);
            acc = fmaf(hv.y, wp[(size_t)(k + 1) * HH], acc);
            acc = fmaf(hv.z, wp[(size_t)(k + 2) * HH], acc);
            acc = fmaf(hv.w, wp[(size_t)(k + 3) * HH], acc);
        }
        float hn = tanhf(acc);
        outn[(size_t)t * HH + j] = hn;
        hbuf[cur ^ 1][j] = hn;
        cur ^= 1;
        __syncthreads();
    }
}

// ---------------------------------------------------------------------------
extern "C" void kernel_launch(void* const* d_in, const int* in_sizes, int n_in,
                              void* d_out, int out_size, void* d_ws, size_t ws_size,
                              hipStream_t stream) {
    const float* x  = (const float*)d_in[0];   // (N, T, D)
    const float* h0 = (const float*)d_in[1];   // (N, H)
    const float* Wx = (const float*)d_in[2];   // (D, H)
    const float* Wh = (const float*)d_in[3];   // (H, H)
    const float* b  = (const float*)d_in[4];   // (H)
    float* out = (float*)d_out;                // (N, T, H)

    const long   M        = (long)NB * TT;               // 65536
    const size_t exch_b   = (size_t)NB * 2 * HH * 8;     // 512 KB
    const size_t wt_b     = (size_t)HH * DD * 2;         // 512 KB
    const size_t xb_b     = (size_t)M * DD * 2;          // 64 MB
    const size_t need_mid = exch_b;                      // pkt scan only
    const size_t need_all = exch_b + wt_b + xb_b;        // + bf16 gemm

    if (ws_size >= need_all) {
        uint64_t*       exch = (uint64_t*)d_ws;
        unsigned short* Wt   = (unsigned short*)((char*)d_ws + exch_b);
        unsigned short* xb   = (unsigned short*)((char*)d_ws + exch_b + wt_b);

        conv_x<<<2048, 256, 0, stream>>>(x, xb, M * DD);
        conv_wt<<<HH, 64, 0, stream>>>(Wx, Wt);
        dim3 gg(M / GBM, HH / GBN);
        gemm_bf16<<<gg, 256, 0, stream>>>(xb, Wt, b, out);
        rnn_scan_pkt<<<256, 1024, 0, stream>>>(Wh, h0, out, exch);
    } else if (ws_size >= need_mid) {
        dim3 g1(M / BM, HH / BN);
        gemm_xw<<<g1, 256, 0, stream>>>(x, Wx, b, out);
        rnn_scan_pkt<<<256, 1024, 0, stream>>>(Wh, h0, out, (uint64_t*)d_ws);
    } else {
        dim3 g1(M / BM, HH / BN);
        gemm_xw<<<g1, 256, 0, stream>>>(x, Wx, b, out);
        rnn_scan_f32<<<NB, 512, 0, stream>>>(Wh, h0, out);
    }
}